// Round 2
// baseline (395.387 us; speedup 1.0000x reference)
//
#include <hip/hip_runtime.h>
#include <math.h>

// ZINB decoder edge kernel.
// Per edge e: h = c_feat[u[e]] (*) g_feat[v[e]]  (64-dim elementwise)
//   mu_  = sigmoid(h.Wm + bm); disp_ = h.Wd + bd; pi = sigmoid(h.Wp + bp)
//   disp = clip(softplus(gs[v]*disp_), 1e-4, 1e4)
//   mu   = cs[u] * clip(exp(gs[v]*mu_) - 1, 1e-5, 1e6)
// Outputs concatenated: mu[E], disp[E], pi[E].
//
// Layout: 16 lanes cooperate on one edge. Each lane holds one float4 of the
// 64-float row (16 lanes * 16B = 256B coalesced, row-aligned). Three dot
// products reduced with __shfl_xor (8/4/2/1 stays inside the 16-lane group).

__global__ __launch_bounds__(256) void zinb_edge_kernel(
    const float* __restrict__ c_feat,
    const float* __restrict__ g_feat,
    const float* __restrict__ cs_factor,
    const float* __restrict__ gs_factor,
    const int* __restrict__ edge_u,
    const int* __restrict__ edge_v,
    const float* __restrict__ W_mean, const float* __restrict__ b_mean,
    const float* __restrict__ W_disp, const float* __restrict__ b_disp,
    const float* __restrict__ W_pi,   const float* __restrict__ b_pi,
    float* __restrict__ out_mu,
    float* __restrict__ out_disp,
    float* __restrict__ out_pi,
    int n_edges)
{
    const int lane16 = threadIdx.x & 15;

    // Constant per-thread weight fragments (64 floats = 16 lanes x float4).
    const float4 wm = ((const float4*)W_mean)[lane16];
    const float4 wd = ((const float4*)W_disp)[lane16];
    const float4 wp = ((const float4*)W_pi)[lane16];
    const float bm = b_mean[0], bd = b_disp[0], bp = b_pi[0];

    const float4* __restrict__ c4 = (const float4*)c_feat;
    const float4* __restrict__ g4 = (const float4*)g_feat;

    const int group   = (int)((blockIdx.x * blockDim.x + threadIdx.x) >> 4);
    const int ngroups = (int)((gridDim.x * blockDim.x) >> 4);

    for (int e = group; e < n_edges; e += ngroups) {
        const int u = edge_u[e];
        const int v = edge_v[e];

        // 256B coalesced row gathers
        const float4 cc = c4[u * 16 + lane16];
        const float4 gg = g4[v * 16 + lane16];

        const float hx = cc.x * gg.x;
        const float hy = cc.y * gg.y;
        const float hz = cc.z * gg.z;
        const float hw = cc.w * gg.w;

        float pm = hx * wm.x + hy * wm.y + hz * wm.z + hw * wm.w;
        float pd = hx * wd.x + hy * wd.y + hz * wd.z + hw * wd.w;
        float pp = hx * wp.x + hy * wp.y + hz * wp.z + hw * wp.w;

        // 16-lane butterfly reduction (stays inside the group for masks < 16)
        #pragma unroll
        for (int off = 8; off >= 1; off >>= 1) {
            pm += __shfl_xor(pm, off);
            pd += __shfl_xor(pd, off);
            pp += __shfl_xor(pp, off);
        }

        if (lane16 == 0) {
            const float gs = gs_factor[v];
            const float cs = cs_factor[u];

            const float mu_  = 1.f / (1.f + expf(-(pm + bm)));
            const float dsp_ = pd + bd;
            const float pi_  = 1.f / (1.f + expf(-(pp + bp)));

            // stable softplus(gs * dsp_)
            const float sx = gs * dsp_;
            const float sp = fmaxf(sx, 0.f) + log1pf(expf(-fabsf(sx)));
            const float disp = fminf(fmaxf(sp, 1e-4f), 1e4f);

            const float mu = cs * fminf(fmaxf(expm1f(gs * mu_), 1e-5f), 1e6f);

            out_mu[e]   = mu;
            out_disp[e] = disp;
            out_pi[e]   = pi_;
        }
    }
}

extern "C" void kernel_launch(void* const* d_in, const int* in_sizes, int n_in,
                              void* d_out, int out_size, void* d_ws, size_t ws_size,
                              hipStream_t stream) {
    const float* c_feat = (const float*)d_in[0];
    const float* g_feat = (const float*)d_in[1];
    const float* cs     = (const float*)d_in[2];
    const float* gs     = (const float*)d_in[3];
    const int*   eu     = (const int*)d_in[4];
    const int*   ev     = (const int*)d_in[5];
    const float* Wm     = (const float*)d_in[6];
    const float* bm     = (const float*)d_in[7];
    const float* Wd     = (const float*)d_in[8];
    const float* bd     = (const float*)d_in[9];
    const float* Wp     = (const float*)d_in[10];
    const float* bp     = (const float*)d_in[11];

    const int E = in_sizes[4];
    float* out_mu   = (float*)d_out;
    float* out_disp = out_mu + E;
    float* out_pi   = out_mu + 2 * (size_t)E;

    dim3 grid(2048), block(256);
    hipLaunchKernelGGL(zinb_edge_kernel, grid, block, 0, stream,
                       c_feat, g_feat, cs, gs, eu, ev,
                       Wm, bm, Wd, bd, Wp, bp,
                       out_mu, out_disp, out_pi, E);
}

// Round 5
// 337.851 us; speedup vs baseline: 1.1703x; 1.1703x over previous
//
#include <hip/hip_runtime.h>
#include <math.h>

// ZINB decoder — one edge per thread.
// Per edge e: h = c_feat[u[e]] (*) g_feat[v[e]]  (64-dim)
//   mu  = cs[u] * clip(exp(gs[v]*sigmoid(h.Wm+bm)) - 1, 1e-5, 1e6)
//   disp= clip(softplus(gs[v]*(h.Wd+bd)), 1e-4, 1e4)
//   pi  = sigmoid(h.Wp+bp)
// Outputs concatenated: mu[E], disp[E], pi[E].
//
// Design (round 3): round-2 baseline was VALU-issue-bound (VALUBusy~100%,
// ~133 wave-VALU instrs/edge) due to 16-lane shuffles + divergent library
// transcendental tail. One-edge-per-thread removes shuffles entirely and
// runs the activation tail at full lane utilization with native-instr math.
// Weights live in LDS (broadcast ds_read_b128, conflict-free). Gathers are
// 16x global_load_dwordx4 per row with immediate offsets.

#define LOG2E 1.44269504088896340736f

__global__ __launch_bounds__(256) void zinb_edge_kernel(
    const float* __restrict__ c_feat,
    const float* __restrict__ g_feat,
    const float* __restrict__ cs_factor,
    const float* __restrict__ gs_factor,
    const int* __restrict__ edge_u,
    const int* __restrict__ edge_v,
    const float* __restrict__ W_mean, const float* __restrict__ b_mean,
    const float* __restrict__ W_disp, const float* __restrict__ b_disp,
    const float* __restrict__ W_pi,   const float* __restrict__ b_pi,
    float* __restrict__ out_mu,
    float* __restrict__ out_disp,
    float* __restrict__ out_pi,
    int n_edges)
{
    // LDS weight table: [chunk k][0..2] = Wm4[k], Wd4[k], Wp4[k]  (48 float4)
    __shared__ float4 wlds[48];
    {
        const int t = threadIdx.x;
        if (t < 48) {
            const int which = t / 16;   // 0=mean, 1=disp, 2=pi
            const int k     = t % 16;
            const float4* src = (which == 0) ? (const float4*)W_mean
                              : (which == 1) ? (const float4*)W_disp
                                             : (const float4*)W_pi;
            wlds[k * 3 + which] = src[k];
        }
    }
    __syncthreads();

    const float bm = b_mean[0], bd = b_disp[0], bp = b_pi[0];

    const float4* __restrict__ c4 = (const float4*)c_feat;
    const float4* __restrict__ g4 = (const float4*)g_feat;

    const int tid    = (int)(blockIdx.x * blockDim.x + threadIdx.x);
    const int stride = (int)(gridDim.x * blockDim.x);

    for (int e = tid; e < n_edges; e += stride) {
        const int u = edge_u[e];
        const int v = edge_v[e];

        const float4* __restrict__ cb = c4 + (size_t)u * 16;
        const float4* __restrict__ gb = g4 + (size_t)v * 16;

        float pm = 0.f, pd = 0.f, pp = 0.f;

        #pragma unroll
        for (int k = 0; k < 16; ++k) {
            const float4 cc = cb[k];
            const float4 gg = gb[k];
            const float4 wm = wlds[k * 3 + 0];
            const float4 wd = wlds[k * 3 + 1];
            const float4 wp = wlds[k * 3 + 2];

            const float hx = cc.x * gg.x;
            const float hy = cc.y * gg.y;
            const float hz = cc.z * gg.z;
            const float hw = cc.w * gg.w;

            pm = fmaf(hx, wm.x, fmaf(hy, wm.y, fmaf(hz, wm.z, fmaf(hw, wm.w, pm))));
            pd = fmaf(hx, wd.x, fmaf(hy, wd.y, fmaf(hz, wd.z, fmaf(hw, wd.w, pd))));
            pp = fmaf(hx, wp.x, fmaf(hy, wp.y, fmaf(hz, wp.z, fmaf(hw, wp.w, pp))));
        }

        const float gs = gs_factor[v];
        const float cs = cs_factor[u];

        // sigmoid via native exp2/rcp
        const float mu_ = __builtin_amdgcn_rcpf(1.f + __expf(-(pm + bm)));
        const float pi_ = __builtin_amdgcn_rcpf(1.f + __expf(-(pp + bp)));

        // disp = clip(softplus(gs*(pd+bd)), 1e-4, 1e4), stable softplus
        const float sx = gs * (pd + bd);
        const float sp = fmaxf(sx, 0.f) + __logf(1.f + __expf(-fabsf(sx)));
        const float disp = fminf(fmaxf(sp, 1e-4f), 1e4f);

        // mu = cs * clip(exp(gs*mu_)-1, 1e-5, 1e6)
        const float mu = cs * fminf(fmaxf(__expf(gs * mu_) - 1.f, 1e-5f), 1e6f);

        out_mu[e]   = mu;
        out_disp[e] = disp;
        out_pi[e]   = pi_;
    }
}

extern "C" void kernel_launch(void* const* d_in, const int* in_sizes, int n_in,
                              void* d_out, int out_size, void* d_ws, size_t ws_size,
                              hipStream_t stream) {
    const float* c_feat = (const float*)d_in[0];
    const float* g_feat = (const float*)d_in[1];
    const float* cs     = (const float*)d_in[2];
    const float* gs     = (const float*)d_in[3];
    const int*   eu     = (const int*)d_in[4];
    const int*   ev     = (const int*)d_in[5];
    const float* Wm     = (const float*)d_in[6];
    const float* bm     = (const float*)d_in[7];
    const float* Wd     = (const float*)d_in[8];
    const float* bd     = (const float*)d_in[9];
    const float* Wp     = (const float*)d_in[10];
    const float* bp     = (const float*)d_in[11];

    const int E = in_sizes[4];
    float* out_mu   = (float*)d_out;
    float* out_disp = out_mu + E;
    float* out_pi   = out_mu + 2 * (size_t)E;

    dim3 grid(2048), block(256);
    hipLaunchKernelGGL(zinb_edge_kernel, grid, block, 0, stream,
                       c_feat, g_feat, cs, gs, eu, ev,
                       Wm, bm, Wd, bd, Wp, bp,
                       out_mu, out_disp, out_pi, E);
}

// Round 6
// 237.804 us; speedup vs baseline: 1.6627x; 1.4207x over previous
//
#include <hip/hip_runtime.h>
#include <math.h>

// ZINB decoder, round 6.
// Round-5 post-mortem: VALUBusy 9.7%, fabric 2.7 TB/s (34%), FETCH 626 MB ->
// bound by L1/TA divergent-gather processing (~1 lane-request/cycle/CU;
// 36 lane-requests/edge). This round halves row-gather requests by packing
// the feature tables to bf16 in d_ws (128 B/row -> 8x16B loads), done by a
// small pack kernel each call. Edge lists / outputs use nontemporal access
// to keep L2 for the gather working set (9 MB bf16 vs 4 MB L2/XCD).
//
// out = [mu[E], disp[E], pi[E]] (f32), math identical to reference.

__device__ __forceinline__ unsigned f2bf(float f) {           // RNE f32->bf16
    unsigned u = __float_as_uint(f);
    return (u + 0x7fffu + ((u >> 16) & 1u)) >> 16;
}
__device__ __forceinline__ unsigned pack2(float lo, float hi) {
    return f2bf(lo) | (f2bf(hi) << 16);
}
__device__ __forceinline__ float blo(unsigned u) { return __uint_as_float(u << 16); }
__device__ __forceinline__ float bhi(unsigned u) { return __uint_as_float(u & 0xFFFF0000u); }

// ---------------- pack kernel: f32 rows -> bf16 rows in d_ws ----------------
__global__ __launch_bounds__(256) void zinb_pack_kernel(
    const float4* __restrict__ c_src, const float4* __restrict__ g_src,
    uint4* __restrict__ c_dst, uint4* __restrict__ g_dst,
    int n_c_groups, int n_total_groups)   // group = 8 floats -> one uint4
{
    const int i = (int)(blockIdx.x * blockDim.x + threadIdx.x);
    if (i >= n_total_groups) return;
    const float4* src; uint4* dst; int j;
    if (i < n_c_groups) { src = c_src; dst = c_dst; j = i; }
    else                { src = g_src; dst = g_dst; j = i - n_c_groups; }
    const float4 a = src[2 * j];
    const float4 b = src[2 * j + 1];
    uint4 o;
    o.x = pack2(a.x, a.y);
    o.y = pack2(a.z, a.w);
    o.z = pack2(b.x, b.y);
    o.w = pack2(b.z, b.w);
    dst[j] = o;
}

// ---------------- main kernel: bf16 gathers ----------------
__global__ __launch_bounds__(256) void zinb_edge_bf16_kernel(
    const uint4* __restrict__ c_pack,   // [n_cells][8] uint4 (64 bf16)
    const uint4* __restrict__ g_pack,   // [n_genes][8]
    const float* __restrict__ cs_factor,
    const float* __restrict__ gs_factor,
    const int* __restrict__ edge_u,
    const int* __restrict__ edge_v,
    const float* __restrict__ W_mean, const float* __restrict__ b_mean,
    const float* __restrict__ W_disp, const float* __restrict__ b_disp,
    const float* __restrict__ W_pi,   const float* __restrict__ b_pi,
    float* __restrict__ out_mu,
    float* __restrict__ out_disp,
    float* __restrict__ out_pi,
    int n_edges)
{
    // LDS weights: chunk k (8 floats) -> wlds[k*6 + which*2 + half]
    __shared__ float4 wlds[48];
    {
        const int t = threadIdx.x;
        if (t < 48) {
            const int which = t / 16;        // 0=mean 1=disp 2=pi
            const int q     = t % 16;        // float4 index within W (0..15)
            const float4* src = (which == 0) ? (const float4*)W_mean
                              : (which == 1) ? (const float4*)W_disp
                                             : (const float4*)W_pi;
            wlds[(q >> 1) * 6 + which * 2 + (q & 1)] = src[q];
        }
    }
    __syncthreads();

    const float bm = b_mean[0], bd = b_disp[0], bp = b_pi[0];

    const int tid    = (int)(blockIdx.x * blockDim.x + threadIdx.x);
    const int stride = (int)(gridDim.x * blockDim.x);

    for (int e = tid; e < n_edges; e += stride) {
        const int u = __builtin_nontemporal_load(edge_u + e);
        const int v = __builtin_nontemporal_load(edge_v + e);

        const uint4* __restrict__ cb = c_pack + (size_t)u * 8;
        const uint4* __restrict__ gb = g_pack + (size_t)v * 8;

        float pm = 0.f, pd = 0.f, pp = 0.f;

        #pragma unroll
        for (int k = 0; k < 8; ++k) {
            const uint4 cu = cb[k];
            const uint4 gu = gb[k];
            const float4 wma = wlds[k * 6 + 0], wmb = wlds[k * 6 + 1];
            const float4 wda = wlds[k * 6 + 2], wdb = wlds[k * 6 + 3];
            const float4 wpa = wlds[k * 6 + 4], wpb = wlds[k * 6 + 5];

            const float h0 = blo(cu.x) * blo(gu.x);
            const float h1 = bhi(cu.x) * bhi(gu.x);
            const float h2 = blo(cu.y) * blo(gu.y);
            const float h3 = bhi(cu.y) * bhi(gu.y);
            const float h4 = blo(cu.z) * blo(gu.z);
            const float h5 = bhi(cu.z) * bhi(gu.z);
            const float h6 = blo(cu.w) * blo(gu.w);
            const float h7 = bhi(cu.w) * bhi(gu.w);

            pm = fmaf(h0, wma.x, fmaf(h1, wma.y, fmaf(h2, wma.z, fmaf(h3, wma.w, pm))));
            pm = fmaf(h4, wmb.x, fmaf(h5, wmb.y, fmaf(h6, wmb.z, fmaf(h7, wmb.w, pm))));
            pd = fmaf(h0, wda.x, fmaf(h1, wda.y, fmaf(h2, wda.z, fmaf(h3, wda.w, pd))));
            pd = fmaf(h4, wdb.x, fmaf(h5, wdb.y, fmaf(h6, wdb.z, fmaf(h7, wdb.w, pd))));
            pp = fmaf(h0, wpa.x, fmaf(h1, wpa.y, fmaf(h2, wpa.z, fmaf(h3, wpa.w, pp))));
            pp = fmaf(h4, wpb.x, fmaf(h5, wpb.y, fmaf(h6, wpb.z, fmaf(h7, wpb.w, pp))));
        }

        const float gs = gs_factor[v];
        const float cs = cs_factor[u];

        const float mu_ = __builtin_amdgcn_rcpf(1.f + __expf(-(pm + bm)));
        const float pi_ = __builtin_amdgcn_rcpf(1.f + __expf(-(pp + bp)));

        const float sx = gs * (pd + bd);
        const float sp = fmaxf(sx, 0.f) + __logf(1.f + __expf(-fabsf(sx)));
        const float disp = fminf(fmaxf(sp, 1e-4f), 1e4f);

        const float mu = cs * fminf(fmaxf(__expf(gs * mu_) - 1.f, 1e-5f), 1e6f);

        __builtin_nontemporal_store(mu,   out_mu + e);
        __builtin_nontemporal_store(disp, out_disp + e);
        __builtin_nontemporal_store(pi_,  out_pi + e);
    }
}

// ---------------- f32 fallback (round-3 kernel) if ws too small ----------------
__global__ __launch_bounds__(256) void zinb_edge_f32_kernel(
    const float* __restrict__ c_feat,
    const float* __restrict__ g_feat,
    const float* __restrict__ cs_factor,
    const float* __restrict__ gs_factor,
    const int* __restrict__ edge_u,
    const int* __restrict__ edge_v,
    const float* __restrict__ W_mean, const float* __restrict__ b_mean,
    const float* __restrict__ W_disp, const float* __restrict__ b_disp,
    const float* __restrict__ W_pi,   const float* __restrict__ b_pi,
    float* __restrict__ out_mu,
    float* __restrict__ out_disp,
    float* __restrict__ out_pi,
    int n_edges)
{
    __shared__ float4 wlds[48];
    {
        const int t = threadIdx.x;
        if (t < 48) {
            const int which = t / 16;
            const int k     = t % 16;
            const float4* src = (which == 0) ? (const float4*)W_mean
                              : (which == 1) ? (const float4*)W_disp
                                             : (const float4*)W_pi;
            wlds[k * 3 + which] = src[k];
        }
    }
    __syncthreads();

    const float bm = b_mean[0], bd = b_disp[0], bp = b_pi[0];
    const float4* __restrict__ c4 = (const float4*)c_feat;
    const float4* __restrict__ g4 = (const float4*)g_feat;

    const int tid    = (int)(blockIdx.x * blockDim.x + threadIdx.x);
    const int stride = (int)(gridDim.x * blockDim.x);

    for (int e = tid; e < n_edges; e += stride) {
        const int u = edge_u[e];
        const int v = edge_v[e];
        const float4* __restrict__ cb = c4 + (size_t)u * 16;
        const float4* __restrict__ gb = g4 + (size_t)v * 16;

        float pm = 0.f, pd = 0.f, pp = 0.f;
        #pragma unroll
        for (int k = 0; k < 16; ++k) {
            const float4 cc = cb[k];
            const float4 gg = gb[k];
            const float4 wm = wlds[k * 3 + 0];
            const float4 wd = wlds[k * 3 + 1];
            const float4 wp = wlds[k * 3 + 2];
            const float hx = cc.x * gg.x;
            const float hy = cc.y * gg.y;
            const float hz = cc.z * gg.z;
            const float hw = cc.w * gg.w;
            pm = fmaf(hx, wm.x, fmaf(hy, wm.y, fmaf(hz, wm.z, fmaf(hw, wm.w, pm))));
            pd = fmaf(hx, wd.x, fmaf(hy, wd.y, fmaf(hz, wd.z, fmaf(hw, wd.w, pd))));
            pp = fmaf(hx, wp.x, fmaf(hy, wp.y, fmaf(hz, wp.z, fmaf(hw, wp.w, pp))));
        }

        const float gs = gs_factor[v];
        const float cs = cs_factor[u];
        const float mu_ = __builtin_amdgcn_rcpf(1.f + __expf(-(pm + bm)));
        const float pi_ = __builtin_amdgcn_rcpf(1.f + __expf(-(pp + bp)));
        const float sx = gs * (pd + bd);
        const float sp = fmaxf(sx, 0.f) + __logf(1.f + __expf(-fabsf(sx)));
        const float disp = fminf(fmaxf(sp, 1e-4f), 1e4f);
        const float mu = cs * fminf(fmaxf(__expf(gs * mu_) - 1.f, 1e-5f), 1e6f);

        out_mu[e]   = mu;
        out_disp[e] = disp;
        out_pi[e]   = pi_;
    }
}

extern "C" void kernel_launch(void* const* d_in, const int* in_sizes, int n_in,
                              void* d_out, int out_size, void* d_ws, size_t ws_size,
                              hipStream_t stream) {
    const float* c_feat = (const float*)d_in[0];
    const float* g_feat = (const float*)d_in[1];
    const float* cs     = (const float*)d_in[2];
    const float* gs     = (const float*)d_in[3];
    const int*   eu     = (const int*)d_in[4];
    const int*   ev     = (const int*)d_in[5];
    const float* Wm     = (const float*)d_in[6];
    const float* bm     = (const float*)d_in[7];
    const float* Wd     = (const float*)d_in[8];
    const float* bd     = (const float*)d_in[9];
    const float* Wp     = (const float*)d_in[10];
    const float* bp     = (const float*)d_in[11];

    const int E       = in_sizes[4];
    const int n_cells = in_sizes[0] / 64;
    const int n_genes = in_sizes[1] / 64;

    float* out_mu   = (float*)d_out;
    float* out_disp = out_mu + E;
    float* out_pi   = out_mu + 2 * (size_t)E;

    const size_t c_bytes = (size_t)n_cells * 64 * 2;   // bf16 rows
    const size_t g_bytes = (size_t)n_genes * 64 * 2;

    if (ws_size >= c_bytes + g_bytes) {
        uint4* c_pack = (uint4*)d_ws;
        uint4* g_pack = (uint4*)((char*)d_ws + c_bytes);

        const int n_c_groups = n_cells * 8;            // 8 floats per group
        const int n_total    = n_c_groups + n_genes * 8;
        dim3 pgrid((n_total + 255) / 256), pblock(256);
        hipLaunchKernelGGL(zinb_pack_kernel, pgrid, pblock, 0, stream,
                           (const float4*)c_feat, (const float4*)g_feat,
                           c_pack, g_pack, n_c_groups, n_total);

        dim3 grid(2048), block(256);
        hipLaunchKernelGGL(zinb_edge_bf16_kernel, grid, block, 0, stream,
                           c_pack, g_pack, cs, gs, eu, ev,
                           Wm, bm, Wd, bd, Wp, bp,
                           out_mu, out_disp, out_pi, E);
    } else {
        dim3 grid(2048), block(256);
        hipLaunchKernelGGL(zinb_edge_f32_kernel, grid, block, 0, stream,
                           c_feat, g_feat, cs, gs, eu, ev,
                           Wm, bm, Wd, bd, Wp, bp,
                           out_mu, out_disp, out_pi, E);
    }
}

// Round 8
// 185.763 us; speedup vs baseline: 2.1284x; 1.2801x over previous
//
#include <hip/hip_runtime.h>
#include <math.h>

// ZINB decoder, round 7.
// Cost model (confirmed r5->r6): time ~ distinct L1-line visits, ~0.6/cycle/CU.
// r6 layout (one edge per thread) visits each 128B row-line 8x (8 divergent
// dwordx4 instrs). This round: 8 lanes per edge, lane l = edge (l>>3), chunk
// (l&7) -> one load instr has 8 consecutive-address lanes per line, which the
// TA coalesces: 2 line-visits/edge for rows (was 16). Reduction over chunks:
// DPP quad_perm xor1/xor2 (VALU) + ds_swizzle xor4 (1 DS op). Sub-phase j's
// octet results kept by lanes k==j  => after 8 sub-phases each lane owns one
// edge (perm = 8k+grp, bijection) and the activation tail runs 64-wide.
// Tables packed to f16 (128B/row); dots via v_pk_mul_f16 + v_dot2_f32_f16.

typedef _Float16 h2 __attribute__((ext_vector_type(2)));

#if __has_builtin(__builtin_amdgcn_fdot2)
__device__ __forceinline__ float fdot2f(h2 a, h2 b, float c) {
    return __builtin_amdgcn_fdot2(a, b, c, false);
}
#else
__device__ __forceinline__ float fdot2f(h2 a, h2 b, float c) {
    return fmaf((float)a.x, (float)b.x, fmaf((float)a.y, (float)b.y, c));
}
#endif

__device__ __forceinline__ float red8(float x) {
#if __has_builtin(__builtin_amdgcn_mov_dpp) && __has_builtin(__builtin_amdgcn_ds_swizzle)
    int t;
    t = __builtin_amdgcn_mov_dpp(__float_as_int(x), 0xB1, 0xF, 0xF, 1); // quad_perm [1,0,3,2] = xor1
    x += __int_as_float(t);
    t = __builtin_amdgcn_mov_dpp(__float_as_int(x), 0x4E, 0xF, 0xF, 1); // quad_perm [2,3,0,1] = xor2
    x += __int_as_float(t);
    t = __builtin_amdgcn_ds_swizzle(__float_as_int(x), 0x101F);         // xor4 (BitMode)
    x += __int_as_float(t);
#else
    x += __shfl_xor(x, 1);
    x += __shfl_xor(x, 2);
    x += __shfl_xor(x, 4);
#endif
    return x;
}

__device__ __forceinline__ unsigned pack2h(float lo, float hi) {
    h2 p = {(_Float16)lo, (_Float16)hi};
    return __builtin_bit_cast(unsigned, p);
}

// ---------------- pack kernel: f32 rows -> f16 rows in d_ws ----------------
__global__ __launch_bounds__(256) void zinb_pack_kernel(
    const float4* __restrict__ c_src, const float4* __restrict__ g_src,
    uint4* __restrict__ c_dst, uint4* __restrict__ g_dst,
    int n_c_groups, int n_total_groups)   // group = 8 floats -> one uint4
{
    const int i = (int)(blockIdx.x * blockDim.x + threadIdx.x);
    if (i >= n_total_groups) return;
    const float4* src; uint4* dst; int j;
    if (i < n_c_groups) { src = c_src; dst = c_dst; j = i; }
    else                { src = g_src; dst = g_dst; j = i - n_c_groups; }
    const float4 a = src[2 * j];
    const float4 b = src[2 * j + 1];
    uint4 o;
    o.x = pack2h(a.x, a.y);
    o.y = pack2h(a.z, a.w);
    o.z = pack2h(b.x, b.y);
    o.w = pack2h(b.z, b.w);
    dst[j] = o;
}

// ---------------- main kernel: 8 lanes per edge, f16 gathers ----------------
__global__ __launch_bounds__(256) void zinb_edge_f16_kernel(
    const uint4* __restrict__ c_pack,   // [n_cells][8] uint4 (64 f16)
    const uint4* __restrict__ g_pack,   // [n_genes][8]
    const float* __restrict__ cs_factor,
    const float* __restrict__ gs_factor,
    const int* __restrict__ edge_u,
    const int* __restrict__ edge_v,
    const float* __restrict__ W_mean, const float* __restrict__ b_mean,
    const float* __restrict__ W_disp, const float* __restrict__ b_disp,
    const float* __restrict__ W_pi,   const float* __restrict__ b_pi,
    float* __restrict__ out_mu,
    float* __restrict__ out_disp,
    float* __restrict__ out_pi,
    int n_edges)
{
    const int lane = (int)(threadIdx.x & 63);
    const int k    = lane & 7;    // chunk within row (elements 8k..8k+7)
    const int grp  = lane >> 3;   // edge within octet

    // Per-lane weight fragments for chunk k (fixed for kernel lifetime).
    h2 wm[4], wd[4], wp[4];
    #pragma unroll
    for (int i = 0; i < 4; ++i) {
        wm[i] = (h2){(_Float16)W_mean[8 * k + 2 * i], (_Float16)W_mean[8 * k + 2 * i + 1]};
        wd[i] = (h2){(_Float16)W_disp[8 * k + 2 * i], (_Float16)W_disp[8 * k + 2 * i + 1]};
        wp[i] = (h2){(_Float16)W_pi  [8 * k + 2 * i], (_Float16)W_pi  [8 * k + 2 * i + 1]};
    }
    const float bm = b_mean[0], bd = b_disp[0], bp = b_pi[0];

    const int perm = (k << 3) | grp;          // this lane's tail-edge offset

    int e0 = (int)(blockIdx.x * blockDim.x + threadIdx.x) & ~63;  // wave base
    const int stride = (int)(gridDim.x * blockDim.x);

    for (; e0 < n_edges; e0 += stride) {
        // ---- prefetch tail operands early (latency hidden by sub-phases) ----
        const int et  = e0 + perm;
        const int etc = (et < n_edges) ? et : (n_edges - 1);
        const int ut = edge_u[etc];
        const int vt = edge_v[etc];
        const float cs_t = cs_factor[ut];
        const float gs_t = gs_factor[vt];

        float pmk = 0.f, pdk = 0.f, ppk = 0.f;

        #pragma unroll
        for (int j = 0; j < 8; ++j) {
            int ej = e0 + 8 * j + grp;
            if (ej >= n_edges) ej = n_edges - 1;   // whole octet clamps together
            const int u = edge_u[ej];              // 8-lane broadcast, L1-hot
            const int v = edge_v[ej];
            const uint4 cu4 = c_pack[(size_t)u * 8 + k];  // 8 lanes share a line
            const uint4 gu4 = g_pack[(size_t)v * 8 + k];

            const h2 c0 = __builtin_bit_cast(h2, cu4.x), g0 = __builtin_bit_cast(h2, gu4.x);
            const h2 c1 = __builtin_bit_cast(h2, cu4.y), g1 = __builtin_bit_cast(h2, gu4.y);
            const h2 c2 = __builtin_bit_cast(h2, cu4.z), g2 = __builtin_bit_cast(h2, gu4.z);
            const h2 c3 = __builtin_bit_cast(h2, cu4.w), g3 = __builtin_bit_cast(h2, gu4.w);
            const h2 h0 = c0 * g0;                 // v_pk_mul_f16
            const h2 h1 = c1 * g1;
            const h2 hh2 = c2 * g2;
            const h2 h3 = c3 * g3;

            float pm = 0.f, pd = 0.f, pp = 0.f;
            pm = fdot2f(h0, wm[0], pm); pm = fdot2f(h1, wm[1], pm);
            pm = fdot2f(hh2, wm[2], pm); pm = fdot2f(h3, wm[3], pm);
            pd = fdot2f(h0, wd[0], pd); pd = fdot2f(h1, wd[1], pd);
            pd = fdot2f(hh2, wd[2], pd); pd = fdot2f(h3, wd[3], pd);
            pp = fdot2f(h0, wp[0], pp); pp = fdot2f(h1, wp[1], pp);
            pp = fdot2f(hh2, wp[2], pp); pp = fdot2f(h3, wp[3], pp);

            pm = red8(pm);
            pd = red8(pd);
            pp = red8(pp);

            if (k == j) { pmk = pm; pdk = pd; ppk = pp; }  // lane's own edge
        }

        // ---- tail: 64 lanes, one edge each ----
        const float mu_ = __builtin_amdgcn_rcpf(1.f + __expf(-(pmk + bm)));
        const float pi_ = __builtin_amdgcn_rcpf(1.f + __expf(-(ppk + bp)));

        const float sx = gs_t * (pdk + bd);
        const float sp = fmaxf(sx, 0.f) + __logf(1.f + __expf(-fabsf(sx)));
        const float disp = fminf(fmaxf(sp, 1e-4f), 1e4f);

        const float mu = cs_t * fminf(fmaxf(__expf(gs_t * mu_) - 1.f, 1e-5f), 1e6f);

        if (et < n_edges) {
            __builtin_nontemporal_store(mu,   out_mu + et);
            __builtin_nontemporal_store(disp, out_disp + et);
            __builtin_nontemporal_store(pi_,  out_pi + et);
        }
    }
}

// ---------------- f32 fallback (round-3/5 kernel, proven) ----------------
__global__ __launch_bounds__(256) void zinb_edge_f32_kernel(
    const float* __restrict__ c_feat,
    const float* __restrict__ g_feat,
    const float* __restrict__ cs_factor,
    const float* __restrict__ gs_factor,
    const int* __restrict__ edge_u,
    const int* __restrict__ edge_v,
    const float* __restrict__ W_mean, const float* __restrict__ b_mean,
    const float* __restrict__ W_disp, const float* __restrict__ b_disp,
    const float* __restrict__ W_pi,   const float* __restrict__ b_pi,
    float* __restrict__ out_mu,
    float* __restrict__ out_disp,
    float* __restrict__ out_pi,
    int n_edges)
{
    __shared__ float4 wlds[48];
    {
        const int t = threadIdx.x;
        if (t < 48) {
            const int which = t / 16;
            const int kk    = t % 16;
            const float4* src = (which == 0) ? (const float4*)W_mean
                              : (which == 1) ? (const float4*)W_disp
                                             : (const float4*)W_pi;
            wlds[kk * 3 + which] = src[kk];
        }
    }
    __syncthreads();

    const float bm = b_mean[0], bd = b_disp[0], bp = b_pi[0];
    const float4* __restrict__ c4 = (const float4*)c_feat;
    const float4* __restrict__ g4 = (const float4*)g_feat;

    const int tid    = (int)(blockIdx.x * blockDim.x + threadIdx.x);
    const int stride = (int)(gridDim.x * blockDim.x);

    for (int e = tid; e < n_edges; e += stride) {
        const int u = edge_u[e];
        const int v = edge_v[e];
        const float4* __restrict__ cb = c4 + (size_t)u * 16;
        const float4* __restrict__ gb = g4 + (size_t)v * 16;

        float pm = 0.f, pd = 0.f, pp = 0.f;
        #pragma unroll
        for (int kk = 0; kk < 16; ++kk) {
            const float4 cc = cb[kk];
            const float4 gg = gb[kk];
            const float4 wmv = wlds[kk * 3 + 0];
            const float4 wdv = wlds[kk * 3 + 1];
            const float4 wpv = wlds[kk * 3 + 2];
            const float hx = cc.x * gg.x;
            const float hy = cc.y * gg.y;
            const float hz = cc.z * gg.z;
            const float hw = cc.w * gg.w;
            pm = fmaf(hx, wmv.x, fmaf(hy, wmv.y, fmaf(hz, wmv.z, fmaf(hw, wmv.w, pm))));
            pd = fmaf(hx, wdv.x, fmaf(hy, wdv.y, fmaf(hz, wdv.z, fmaf(hw, wdv.w, pd))));
            pp = fmaf(hx, wpv.x, fmaf(hy, wpv.y, fmaf(hz, wpv.z, fmaf(hw, wpv.w, pp))));
        }

        const float gs = gs_factor[v];
        const float cs = cs_factor[u];
        const float mu_ = __builtin_amdgcn_rcpf(1.f + __expf(-(pm + bm)));
        const float pi_ = __builtin_amdgcn_rcpf(1.f + __expf(-(pp + bp)));
        const float sx = gs * (pd + bd);
        const float sp = fmaxf(sx, 0.f) + __logf(1.f + __expf(-fabsf(sx)));
        const float disp = fminf(fmaxf(sp, 1e-4f), 1e4f);
        const float mu = cs * fminf(fmaxf(__expf(gs * mu_) - 1.f, 1e-5f), 1e6f);

        out_mu[e]   = mu;
        out_disp[e] = disp;
        out_pi[e]   = pi_;
    }
}

extern "C" void kernel_launch(void* const* d_in, const int* in_sizes, int n_in,
                              void* d_out, int out_size, void* d_ws, size_t ws_size,
                              hipStream_t stream) {
    const float* c_feat = (const float*)d_in[0];
    const float* g_feat = (const float*)d_in[1];
    const float* cs     = (const float*)d_in[2];
    const float* gs     = (const float*)d_in[3];
    const int*   eu     = (const int*)d_in[4];
    const int*   ev     = (const int*)d_in[5];
    const float* Wm     = (const float*)d_in[6];
    const float* bm     = (const float*)d_in[7];
    const float* Wd     = (const float*)d_in[8];
    const float* bd     = (const float*)d_in[9];
    const float* Wp     = (const float*)d_in[10];
    const float* bp     = (const float*)d_in[11];

    const int E       = in_sizes[4];
    const int n_cells = in_sizes[0] / 64;
    const int n_genes = in_sizes[1] / 64;

    float* out_mu   = (float*)d_out;
    float* out_disp = out_mu + E;
    float* out_pi   = out_mu + 2 * (size_t)E;

    const size_t c_bytes = (size_t)n_cells * 64 * 2;   // f16 rows (128 B each)
    const size_t g_bytes = (size_t)n_genes * 64 * 2;

    if (ws_size >= c_bytes + g_bytes) {
        uint4* c_pack = (uint4*)d_ws;
        uint4* g_pack = (uint4*)((char*)d_ws + c_bytes);

        const int n_c_groups = n_cells * 8;            // 8 floats per group
        const int n_total    = n_c_groups + n_genes * 8;
        dim3 pgrid((n_total + 255) / 256), pblock(256);
        hipLaunchKernelGGL(zinb_pack_kernel, pgrid, pblock, 0, stream,
                           (const float4*)c_feat, (const float4*)g_feat,
                           c_pack, g_pack, n_c_groups, n_total);

        dim3 grid(2048), block(256);
        hipLaunchKernelGGL(zinb_edge_f16_kernel, grid, block, 0, stream,
                           c_pack, g_pack, cs, gs, eu, ev,
                           Wm, bm, Wd, bd, Wp, bp,
                           out_mu, out_disp, out_pi, E);
    } else {
        dim3 grid(2048), block(256);
        hipLaunchKernelGGL(zinb_edge_f32_kernel, grid, block, 0, stream,
                           c_feat, g_feat, cs, gs, eu, ev,
                           Wm, bm, Wd, bd, Wp, bp,
                           out_mu, out_disp, out_pi, E);
    }
}